// Round 2
// baseline (164.492 us; speedup 1.0000x reference)
//
#include <hip/hip_runtime.h>

static constexpr int BB = 16;
static constexpr int NN = 256;
static constexpr int DD = 128;

// q = x@Wq^T + bq ; k = x@Wk^T ; v = x@Wv^T.  Outputs: eq=exp(-q), ek=exp(-k), v raw.
// grid = 3 m * 16 b * 16 row-tiles = 768 blocks, 256 threads.
__global__ __launch_bounds__(256) void qkv_kernel(
    const float* __restrict__ x,
    const float* __restrict__ Wq, const float* __restrict__ bq,
    const float* __restrict__ Wk, const float* __restrict__ Wv,
    float* __restrict__ eq, float* __restrict__ ek, float* __restrict__ vv)
{
    __shared__ float xs[16][DD];
    const int bid = blockIdx.x;
    const int m   = bid % 3;          // uniform per block — no divergence
    const int rb  = bid / 3;          // 0..255
    const int b   = rb >> 4;
    const int r0  = (rb & 15) << 4;   // 16-row tile
    const int t   = threadIdx.x;

    const float4* xg = (const float4*)(x + ((size_t)(b * NN + r0)) * DD);
    float4* xsv = (float4*)&xs[0][0];
    xsv[t]       = xg[t];             // 512 float4 total, 2 per thread, coalesced
    xsv[t + 256] = xg[t + 256];
    __syncthreads();

    const int te = t & 31;            // e = te*4 + ee
    const int tr = t >> 5;            // rows tr*2, tr*2+1
    const float* W = (m == 0) ? Wq : (m == 1) ? Wk : Wv;
    float*      op = (m == 0) ? eq : (m == 1) ? ek : vv;

    float acc[2][4] = {};
    const float* x0 = &xs[tr * 2][0];
    const float* x1 = &xs[tr * 2 + 1][0];
    #pragma unroll 4
    for (int d4 = 0; d4 < DD / 4; ++d4) {
        const float4 xa = *(const float4*)(x0 + (d4 << 2));   // LDS broadcast (2 addrs/wave)
        const float4 xb = *(const float4*)(x1 + (d4 << 2));
        #pragma unroll
        for (int ee = 0; ee < 4; ++ee) {
            const float4 w = *(const float4*)(W + (size_t)(te * 4 + ee) * DD + (d4 << 2));
            acc[0][ee] = fmaf(xa.x, w.x, fmaf(xa.y, w.y, fmaf(xa.z, w.z, fmaf(xa.w, w.w, acc[0][ee]))));
            acc[1][ee] = fmaf(xb.x, w.x, fmaf(xb.y, w.y, fmaf(xb.z, w.z, fmaf(xb.w, w.w, acc[1][ee]))));
        }
    }

    float4 bq4 = make_float4(0.f, 0.f, 0.f, 0.f);
    if (m == 0) bq4 = ((const float4*)bq)[te];
    #pragma unroll
    for (int r = 0; r < 2; ++r) {
        float4 o;
        if (m == 0) {
            o.x = __expf(-(acc[r][0] + bq4.x));
            o.y = __expf(-(acc[r][1] + bq4.y));
            o.z = __expf(-(acc[r][2] + bq4.z));
            o.w = __expf(-(acc[r][3] + bq4.w));
        } else if (m == 1) {
            o.x = __expf(-acc[r][0]);
            o.y = __expf(-acc[r][1]);
            o.z = __expf(-acc[r][2]);
            o.w = __expf(-acc[r][3]);
        } else {
            o = make_float4(acc[r][0], acc[r][1], acc[r][2], acc[r][3]);
        }
        *(float4*)(op + ((size_t)(b * NN + r0 + tr * 2 + r)) * DD + te * 4) = o;  // coalesced
    }
}

// One block per (b, 8-j tile). 512 threads (8 waves), grid = 16*32 = 512 (2 blocks/CU).
// Phase B: s[i][j] = edge ? sum_d We_d / (1 + ek[i,d]*eq[j,d]) : 0.5*sum(We)
// Phase C: softmax over i per j. Phase D: out[j][d] = sum_i a * v[i][d].
// No K/V LDS staging — each block reads ek/v exactly once; L2 serves re-reads.
__global__ __launch_bounds__(512) void attn_kernel(
    const int* __restrict__ A, const float* __restrict__ We,
    const float* __restrict__ eq, const float* __restrict__ ek,
    const float* __restrict__ vv, float* __restrict__ out)
{
    __shared__ float eqs[8][132];
    __shared__ float wes[DD];
    __shared__ float ssm[8][264];
    __shared__ float smC;

    const int b  = blockIdx.x >> 5;
    const int j0 = (blockIdx.x & 31) << 3;
    const int t  = threadIdx.x;

    // ---- Phase A: stage q rows + We, compute C = 0.5*sum(We) ----
    if (t < 256) {
        const int row = t >> 5, col = (t & 31) << 2;
        *(float4*)&eqs[row][col] =
            *(const float4*)(eq + ((size_t)(b * NN + j0 + row)) * DD + col);
    } else if (t < 288) {
        const int l = t - 256;
        *(float4*)&wes[l << 2] = ((const float4*)We)[l];
    } else if (t >= 448) {
        const int lane = t - 448;
        float w = We[lane] + We[lane + 64];
        #pragma unroll
        for (int o = 32; o > 0; o >>= 1) w += __shfl_xor(w, o);
        if (lane == 0) smC = 0.5f * w;
    }
    __syncthreads();

    const float C  = smC;
    const int jp = t & 3;            // handles j_local = jp and jp+4
    const int ir = t >> 2;           // 0..127

    #pragma unroll
    for (int it = 0; it < 2; ++it) {
        const int i = (it << 7) + ir;
        const float4* ekr = (const float4*)(ek + ((size_t)(b * NN + i)) * DD);
        const int arow = ((b * NN) + i) * NN + j0;
        const int a0 = A[arow + jp];
        const int a1 = A[arow + jp + 4];
        float acc0 = 0.f, acc1 = 0.f;
        #pragma unroll 8
        for (int d4 = 0; d4 < DD / 4; ++d4) {
            const float4 kv = ekr[d4];
            const float4 we = *(const float4*)&wes[d4 << 2];
            const float4 q0 = *(const float4*)&eqs[jp][d4 << 2];
            const float4 q1 = *(const float4*)&eqs[jp + 4][d4 << 2];
            acc0 += we.x * __builtin_amdgcn_rcpf(fmaf(kv.x, q0.x, 1.0f))
                  + we.y * __builtin_amdgcn_rcpf(fmaf(kv.y, q0.y, 1.0f))
                  + we.z * __builtin_amdgcn_rcpf(fmaf(kv.z, q0.z, 1.0f))
                  + we.w * __builtin_amdgcn_rcpf(fmaf(kv.w, q0.w, 1.0f));
            acc1 += we.x * __builtin_amdgcn_rcpf(fmaf(kv.x, q1.x, 1.0f))
                  + we.y * __builtin_amdgcn_rcpf(fmaf(kv.y, q1.y, 1.0f))
                  + we.z * __builtin_amdgcn_rcpf(fmaf(kv.z, q1.z, 1.0f))
                  + we.w * __builtin_amdgcn_rcpf(fmaf(kv.w, q1.w, 1.0f));
        }
        ssm[jp][i]     = (a0 == 1) ? acc0 : C;
        ssm[jp + 4][i] = (a1 == 1) ? acc1 : C;
    }
    __syncthreads();

    // ---- Phase C: softmax over i per j ----
    {
        const int j = t >> 6, c = t & 63;   // 64 lanes per j, 4 i's each (stride 64)
        float vals[4];
        float mx = -1e30f;
        #pragma unroll
        for (int u = 0; u < 4; ++u) { vals[u] = ssm[j][c + (u << 6)]; mx = fmaxf(mx, vals[u]); }
        #pragma unroll
        for (int o = 32; o > 0; o >>= 1) mx = fmaxf(mx, __shfl_xor(mx, o));
        float sum = 0.0f;
        #pragma unroll
        for (int u = 0; u < 4; ++u) { vals[u] = __expf(vals[u] - mx); sum += vals[u]; }
        #pragma unroll
        for (int o = 32; o > 0; o >>= 1) sum += __shfl_xor(sum, o);
        const float inv = __builtin_amdgcn_rcpf(sum);
        #pragma unroll
        for (int u = 0; u < 4; ++u) ssm[j][c + (u << 6)] = vals[u] * inv;
    }
    __syncthreads();

    // ---- Phase D: out[j][d] = sum_i a[j][i] * v[i][d] ----
    {
        const int jd = t >> 6, cd = t & 63;     // d = 2*cd, 2*cd+1
        const float* vb = vv + (size_t)b * NN * DD + (cd << 1);
        float o0 = 0.f, o1 = 0.f;
        #pragma unroll 8
        for (int i = 0; i < NN; ++i) {
            const float a = ssm[jd][i];          // LDS broadcast (jd uniform per wave)
            const float2 v2 = *(const float2*)(vb + (size_t)i * DD);  // full row per wave
            o0 = fmaf(a, v2.x, o0);
            o1 = fmaf(a, v2.y, o1);
        }
        *(float2*)(out + ((size_t)(b * NN + j0 + jd)) * DD + (cd << 1)) = make_float2(o0, o1);
    }
}

extern "C" void kernel_launch(void* const* d_in, const int* in_sizes, int n_in,
                              void* d_out, int out_size, void* d_ws, size_t ws_size,
                              hipStream_t stream)
{
    const float* x  = (const float*)d_in[0];
    const int*   A  = (const int*)  d_in[1];
    const float* Wq = (const float*)d_in[2];
    const float* bq = (const float*)d_in[3];
    const float* Wk = (const float*)d_in[4];
    const float* Wv = (const float*)d_in[5];
    const float* We = (const float*)d_in[6];
    float* out = (float*)d_out;

    float* eq = (float*)d_ws;
    float* ek = eq + (size_t)BB * NN * DD;
    float* vv = ek + (size_t)BB * NN * DD;

    qkv_kernel<<<3 * BB * (NN / 16), 256, 0, stream>>>(x, Wq, bq, Wk, Wv, eq, ek, vv);
    attn_kernel<<<BB * (NN / 8), 512, 0, stream>>>(A, We, eq, ek, vv, out);
}